// Round 1
// baseline (906.293 us; speedup 1.0000x reference)
//
#include <hip/hip_runtime.h>

#define NA 50000
#define NP 1000000
#define FA 75
#define FP 14
#define H  50
#define H2 100

// ---------------------------------------------------------------------------
// K1: per-atom precompute.  AA = relu(af @ W_AA + b_AA)   [NA,H]
//                           U  = af @ W_AP[0:75,:]        [NA,H] (no bias/relu)
//                           V  = af @ W_AP[75:150,:]      [NA,H]
// wave-per-atom, lanes 0..49 each own one output column h.
// ---------------------------------------------------------------------------
__global__ __launch_bounds__(256) void k_atom_pre(
    const float* __restrict__ af,
    const float* __restrict__ W_AA, const float* __restrict__ b_AA,
    const float* __restrict__ W_AP,
    float* __restrict__ AA, float* __restrict__ U, float* __restrict__ V)
{
    int wave = (blockIdx.x * 256 + threadIdx.x) >> 6;   // atom id, 0..49999
    int lane = threadIdx.x & 63;
    if (wave >= NA) return;
    const float* afr = af + wave * FA;
    if (lane < H) {
        float accA = b_AA[lane];
        float accU = 0.f, accV = 0.f;
        #pragma unroll 5
        for (int k = 0; k < FA; ++k) {
            float a = afr[k];                       // broadcast load
            accA += a * W_AA[k * H + lane];
            accU += a * W_AP[k * H + lane];
            accV += a * W_AP[(FA + k) * H + lane];
        }
        AA[wave * H + lane] = fmaxf(accA, 0.f);
        U[wave * H + lane]  = accU;
        V[wave * H + lane]  = accV;
    }
}

// ---------------------------------------------------------------------------
// K2: per-pair fused:  PP = relu(pf @ W_PP + b_PP)
//                      APs = relu(U[i]+V[j]+b_AP) + relu(U[j]+V[i]+b_AP)
//                      P  = relu([APs, PP] @ W_P + b_P)
// wave-per-pair; W_P column (100 floats) + W_PP column (14) held in VGPRs;
// x[100] exchanged through a per-wave LDS row.
// ---------------------------------------------------------------------------
#define PPW 16   // pairs per wave; 4 waves/block -> 64 pairs/block
__global__ __launch_bounds__(256) void k_pairs(
    const float* __restrict__ pf, const int* __restrict__ a2p,
    const float* __restrict__ U, const float* __restrict__ V,
    const float* __restrict__ W_PP, const float* __restrict__ b_PP,
    const float* __restrict__ b_AP,
    const float* __restrict__ W_P, const float* __restrict__ b_P,
    float* __restrict__ Pout)
{
    __shared__ float sX[4][H2];
    int w = threadIdx.x >> 6;
    int lane = threadIdx.x & 63;
    int base = blockIdx.x * (4 * PPW) + w * PPW;

    float wpp[FP], wp[H2];
    float bpp = 0.f, bap = 0.f, bp = 0.f;
    if (lane < H) {
        bpp = b_PP[lane]; bap = b_AP[lane]; bp = b_P[lane];
        #pragma unroll
        for (int k = 0; k < FP; ++k) wpp[k] = W_PP[k * H + lane];
        #pragma unroll
        for (int k = 0; k < H2; ++k) wp[k] = W_P[k * H + lane];
    }

    for (int it = 0; it < PPW; ++it) {
        int p = base + it;
        const float* pfr = pf + (long)p * FP;
        int i = a2p[2 * p];
        int j = a2p[2 * p + 1];
        if (lane < H) {
            float accPP = bpp;
            #pragma unroll
            for (int k = 0; k < FP; ++k) accPP += pfr[k] * wpp[k];
            accPP = fmaxf(accPP, 0.f);
            float ui = U[i * H + lane], vj = V[j * H + lane];
            float uj = U[j * H + lane], vi = V[i * H + lane];
            float aps = fmaxf(ui + vj + bap, 0.f) + fmaxf(uj + vi + bap, 0.f);
            sX[w][lane]     = aps;
            sX[w][H + lane] = accPP;
        }
        __syncthreads();
        if (lane < H) {
            float acc = bp;
            #pragma unroll
            for (int k = 0; k < H2; ++k) acc += sX[w][k] * wp[k];
            Pout[(long)p * H + lane] = fmaxf(acc, 0.f);
        }
        __syncthreads();
    }
}

// ---------------------------------------------------------------------------
// K3: per-atom:  pa_sum = sum over segment of relu(pf@W_PA + b_PA)
//                A = relu([AA, pa_sum] @ W_A + b_A)
// wave-per-atom; segment range found by binary search on sorted pair_seg.
// ---------------------------------------------------------------------------
__global__ __launch_bounds__(256) void k_atoms(
    const float* __restrict__ pf, const int* __restrict__ seg,
    const float* __restrict__ AA,
    const float* __restrict__ W_PA, const float* __restrict__ b_PA,
    const float* __restrict__ W_A, const float* __restrict__ b_A,
    float* __restrict__ Aout)
{
    __shared__ float sX[4][H];
    int w = threadIdx.x >> 6;
    int lane = threadIdx.x & 63;
    int a = blockIdx.x * 4 + w;    // grid is exactly NA/4 blocks

    // lower_bound(seg, a) and lower_bound(seg, a+1)
    int lo = 0, hi = NP;
    while (lo < hi) { int mid = (lo + hi) >> 1; if (seg[mid] < a) lo = mid + 1; else hi = mid; }
    int start = lo;
    hi = NP;
    while (lo < hi) { int mid = (lo + hi) >> 1; if (seg[mid] < a + 1) lo = mid + 1; else hi = mid; }
    int end = lo;

    float wpa[FP], wa[H2];
    float bpa = 0.f, ba = 0.f;
    if (lane < H) {
        bpa = b_PA[lane]; ba = b_A[lane];
        #pragma unroll
        for (int k = 0; k < FP; ++k) wpa[k] = W_PA[k * H + lane];
        #pragma unroll
        for (int k = 0; k < H2; ++k) wa[k] = W_A[k * H + lane];
    }

    if (lane < H) {
        float accPA = 0.f;
        for (int p = start; p < end; ++p) {
            const float* pfr = pf + (long)p * FP;
            float s = bpa;
            #pragma unroll
            for (int k = 0; k < FP; ++k) s += pfr[k] * wpa[k];
            accPA += fmaxf(s, 0.f);
        }
        sX[w][lane] = accPA;
    }
    __syncthreads();
    if (lane < H) {
        float acc = ba;
        const float* aar = AA + a * H;
        #pragma unroll
        for (int k = 0; k < H; ++k)  acc += aar[k] * wa[k];
        #pragma unroll
        for (int k = 0; k < H; ++k)  acc += sX[w][k] * wa[H + k];
        Aout[a * H + lane] = fmaxf(acc, 0.f);
    }
}

// ---------------------------------------------------------------------------
extern "C" void kernel_launch(void* const* d_in, const int* in_sizes, int n_in,
                              void* d_out, int out_size, void* d_ws, size_t ws_size,
                              hipStream_t stream)
{
    const float* af   = (const float*)d_in[0];
    const float* pf   = (const float*)d_in[1];
    const int*   seg  = (const int*)d_in[2];
    const int*   a2p  = (const int*)d_in[3];
    const float* W_AA = (const float*)d_in[4];
    const float* b_AA = (const float*)d_in[5];
    const float* W_PA = (const float*)d_in[6];
    const float* b_PA = (const float*)d_in[7];
    const float* W_A  = (const float*)d_in[8];
    const float* b_A  = (const float*)d_in[9];
    const float* W_AP = (const float*)d_in[10];
    const float* b_AP = (const float*)d_in[11];
    const float* W_PP = (const float*)d_in[12];
    const float* b_PP = (const float*)d_in[13];
    const float* W_P  = (const float*)d_in[14];
    const float* b_P  = (const float*)d_in[15];

    float* Aout = (float*)d_out;                 // [NA*H]
    float* Pout = (float*)d_out + (long)NA * H;  // [NP*H]

    float* AA = (float*)d_ws;          // NA*H floats
    float* U  = AA + (long)NA * H;     // NA*H
    float* V  = U  + (long)NA * H;     // NA*H

    k_atom_pre<<<(NA + 3) / 4, 256, 0, stream>>>(af, W_AA, b_AA, W_AP, AA, U, V);
    k_pairs<<<NP / (4 * PPW), 256, 0, stream>>>(pf, a2p, U, V, W_PP, b_PP, b_AP, W_P, b_P, Pout);
    k_atoms<<<NA / 4, 256, 0, stream>>>(pf, seg, AA, W_PA, b_PA, W_A, b_A, Aout);
}

// Round 2
// 423.791 us; speedup vs baseline: 2.1385x; 2.1385x over previous
//
#include <hip/hip_runtime.h>
#include <hip/hip_bf16.h>

#define NA 50000
#define NP 1000000
#define FA 75
#define FP 14
#define H  50

typedef __attribute__((ext_vector_type(8))) short short8;
typedef __attribute__((ext_vector_type(4))) float f32x4;

__device__ __forceinline__ ushort f2bf(float f) {
    union { float f; unsigned u; } v; v.f = f;
    unsigned r = v.u + 0x7FFF + ((v.u >> 16) & 1);   // RNE
    return (ushort)(r >> 16);
}

// ---------------------------------------------------------------------------
// K0: pack weights into MFMA B-fragment order (bf16), zero-padded.
// B-frag layout for 16x16x32: lane l, elem j -> W[k = tk*32+(l>>4)*8+j][col = tn*16+(l&15)]
// WPf/WAf: [tk=4][tn=4][64][8]  (K=128 pad from 100, N=64 pad from 50)
// W2f:     [tn=8][64][8]        (K=32 pad from 14; tn 0..3 = W_PP cols, 4..7 = W_PA cols)
// ---------------------------------------------------------------------------
__global__ __launch_bounds__(256) void k_prep_frags(
    const float* __restrict__ W_P, const float* __restrict__ W_A,
    const float* __restrict__ W_PP, const float* __restrict__ W_PA,
    ushort* __restrict__ WPf, ushort* __restrict__ WAf, ushort* __restrict__ W2f)
{
    int t = threadIdx.x;
    for (int idx = t; idx < 4*4*64*8; idx += 256) {
        int j = idx & 7, l = (idx >> 3) & 63, tn = (idx >> 9) & 3, tk = idx >> 11;
        int k = tk*32 + (l>>4)*8 + j;
        int c = tn*16 + (l&15);
        ushort vp = 0, va = 0;
        if (k < 100 && c < 50) { vp = f2bf(W_P[k*50+c]); va = f2bf(W_A[k*50+c]); }
        WPf[idx] = vp; WAf[idx] = va;
    }
    for (int idx = t; idx < 8*64*8; idx += 256) {
        int j = idx & 7, l = (idx >> 3) & 63, tn = idx >> 9;
        int k = (l>>4)*8 + j;
        int c = (tn&3)*16 + (l&15);
        ushort v = 0;
        if (k < 14 && c < 50) v = f2bf(tn < 4 ? W_PP[k*50+c] : W_PA[k*50+c]);
        W2f[idx] = v;
    }
}

// ---------------------------------------------------------------------------
// K1: per-atom precompute.  AA = relu(af@W_AA+b), U = af@W_AP[0:75], V = af@W_AP[75:150]
// ---------------------------------------------------------------------------
__global__ __launch_bounds__(256) void k_atom_pre(
    const float* __restrict__ af,
    const float* __restrict__ W_AA, const float* __restrict__ b_AA,
    const float* __restrict__ W_AP,
    float* __restrict__ AA, float* __restrict__ U, float* __restrict__ V)
{
    int wave = (blockIdx.x * 256 + threadIdx.x) >> 6;
    int lane = threadIdx.x & 63;
    if (wave >= NA) return;
    const float* afr = af + (size_t)wave * FA;
    if (lane < H) {
        float accA = b_AA[lane], accU = 0.f, accV = 0.f;
        #pragma unroll 5
        for (int k = 0; k < FA; ++k) {
            float a = afr[k];
            accA += a * W_AA[k * H + lane];
            accU += a * W_AP[k * H + lane];
            accV += a * W_AP[(FA + k) * H + lane];
        }
        AA[(size_t)wave * H + lane] = fmaxf(accA, 0.f);
        U[(size_t)wave * H + lane]  = accU;
        V[(size_t)wave * H + lane]  = accV;
    }
}

// ---------------------------------------------------------------------------
// K2: 64 pairs per block (4 waves).
//   X[64][128] bf16 in LDS: [APs | PP | 0-pad];  PA[64][50] fp32 in LDS.
//   PP,PA via one MFMA pass (K=32); P = relu(X@W_P+b) via 16 MFMA/wave;
//   PA segment-summed (seg sorted) with atomics into PAsum.
// ---------------------------------------------------------------------------
__global__ __launch_bounds__(256) void k_pairs(
    const float* __restrict__ pf, const int* __restrict__ seg, const int* __restrict__ a2p,
    const float* __restrict__ U, const float* __restrict__ V,
    const float* __restrict__ b_PP, const float* __restrict__ b_PA,
    const float* __restrict__ b_AP, const float* __restrict__ b_P,
    const ushort* __restrict__ WPf, const ushort* __restrict__ W2f,
    float* __restrict__ PAsum, float* __restrict__ Pout)
{
    __shared__ __align__(16) ushort sPFb[64][40];   // pf bf16, K-pad to 32 (+8 row pad)
    __shared__ __align__(16) ushort sX[64][136];    // X bf16, K=128 (+8 row pad)
    __shared__ float sPA[64][50];
    __shared__ int sSeg[64];

    const int t = threadIdx.x;
    const int w = t >> 6, lane = t & 63;
    const int p0 = blockIdx.x * 64;
    const int row0 = w * 16;

    for (int idx = t; idx < 64*32; idx += 256) {
        int r = idx >> 5, c = idx & 31;
        sPFb[r][c] = (c < FP) ? f2bf(pf[(size_t)(p0 + r) * FP + c]) : (ushort)0;
    }
    if (t < 64) sSeg[t] = seg[p0 + t];
    for (int idx = t; idx < 64*28; idx += 256) {    // zero X K-pad cols 100..127
        int r = idx / 28, c = 100 + idx % 28;
        sX[r][c] = 0;
    }
    __syncthreads();

    // ---- APs = relu(U[i]+V[j]+b) + relu(U[j]+V[i]+b) -> sX[:,0:50] ----
    float bap = (lane < H) ? b_AP[lane] : 0.f;
    #pragma unroll 4
    for (int it = 0; it < 16; ++it) {
        int p = p0 + row0 + it;
        int i = a2p[2*p], j = a2p[2*p+1];
        if (lane < H) {
            float ui = U[(size_t)i*H + lane], vj = V[(size_t)j*H + lane];
            float uj = U[(size_t)j*H + lane], vi = V[(size_t)i*H + lane];
            float aps = fmaxf(ui + vj + bap, 0.f) + fmaxf(uj + vi + bap, 0.f);
            sX[row0 + it][lane] = f2bf(aps);
        }
    }

    // ---- PP -> sX[:,50:100] (bf16), PA -> sPA (fp32), one K=32 MFMA pass ----
    {
        short8 a = *(const short8*)&sPFb[row0 + (lane&15)][(lane>>4)*8];
        const short8* B = (const short8*)W2f;
        #pragma unroll
        for (int tn = 0; tn < 8; ++tn) {
            f32x4 c = {0.f, 0.f, 0.f, 0.f};
            short8 b = B[tn*64 + lane];
            c = __builtin_amdgcn_mfma_f32_16x16x32_bf16(a, b, c, 0, 0, 0);
            int col = (tn&3)*16 + (lane&15);
            if (col < H) {
                float bias = (tn < 4) ? b_PP[col] : b_PA[col];
                #pragma unroll
                for (int reg = 0; reg < 4; ++reg) {
                    int row = row0 + (lane>>4)*4 + reg;
                    float v = fmaxf(c[reg] + bias, 0.f);
                    if (tn < 4) sX[row][H + col] = f2bf(v);
                    else        sPA[row][col] = v;
                }
            }
        }
    }
    __syncthreads();

    // ---- P = relu(X @ W_P + b_P), M=64 N=64 K=128 ----
    {
        short8 afr[4];
        #pragma unroll
        for (int tk = 0; tk < 4; ++tk)
            afr[tk] = *(const short8*)&sX[row0 + (lane&15)][tk*32 + (lane>>4)*8];
        const short8* B = (const short8*)WPf;
        f32x4 acc[4];
        #pragma unroll
        for (int tn = 0; tn < 4; ++tn) acc[tn] = (f32x4){0.f, 0.f, 0.f, 0.f};
        #pragma unroll
        for (int tk = 0; tk < 4; ++tk) {
            #pragma unroll
            for (int tn = 0; tn < 4; ++tn) {
                short8 b = B[(tk*4 + tn)*64 + lane];
                acc[tn] = __builtin_amdgcn_mfma_f32_16x16x32_bf16(afr[tk], b, acc[tn], 0, 0, 0);
            }
        }
        #pragma unroll
        for (int tn = 0; tn < 4; ++tn) {
            int col = tn*16 + (lane&15);
            if (col < H) {
                float bp = b_P[col];
                #pragma unroll
                for (int reg = 0; reg < 4; ++reg) {
                    int row = row0 + (lane>>4)*4 + reg;
                    Pout[(size_t)(p0 + row)*H + col] = fmaxf(acc[tn][reg] + bp, 0.f);
                }
            }
        }
    }

    // ---- segment-sum PA (seg sorted): run-length within 16-row strips ----
    if (t < 200) {
        int c = t % 50, q = t / 50;
        int r0 = q * 16;
        int cur = sSeg[r0];
        float acc = 0.f;
        for (int r = r0; r < r0 + 16; ++r) {
            int s = sSeg[r];
            if (s != cur) { atomicAdd(&PAsum[(size_t)cur*H + c], acc); acc = 0.f; cur = s; }
            acc += sPA[r][c];
        }
        atomicAdd(&PAsum[(size_t)cur*H + c], acc);
    }
}

// ---------------------------------------------------------------------------
// K3: A = relu([AA | PAsum] @ W_A + b_A), 64 atoms/block, same MFMA pattern.
// ---------------------------------------------------------------------------
__global__ __launch_bounds__(256) void k_A(
    const float* __restrict__ AA, const float* __restrict__ PAsum,
    const ushort* __restrict__ WAf, const float* __restrict__ b_A,
    float* __restrict__ Aout)
{
    __shared__ __align__(16) ushort sX[64][136];
    const int t = threadIdx.x, lane = t & 63, w = t >> 6;
    const int a0 = blockIdx.x * 64;
    const int row0 = w * 16;

    for (int idx = t; idx < 64*50; idx += 256) {
        int r = idx / 50, c = idx % 50;
        int rg = a0 + r;
        float aa = 0.f, ps = 0.f;
        if (rg < NA) { aa = AA[(size_t)rg*H + c]; ps = PAsum[(size_t)rg*H + c]; }
        sX[r][c] = f2bf(aa);
        sX[r][H + c] = f2bf(ps);
    }
    for (int idx = t; idx < 64*28; idx += 256) {
        int r = idx / 28, c = 100 + idx % 28;
        sX[r][c] = 0;
    }
    __syncthreads();

    short8 afr[4];
    #pragma unroll
    for (int tk = 0; tk < 4; ++tk)
        afr[tk] = *(const short8*)&sX[row0 + (lane&15)][tk*32 + (lane>>4)*8];
    const short8* B = (const short8*)WAf;
    f32x4 acc[4];
    #pragma unroll
    for (int tn = 0; tn < 4; ++tn) acc[tn] = (f32x4){0.f, 0.f, 0.f, 0.f};
    #pragma unroll
    for (int tk = 0; tk < 4; ++tk) {
        #pragma unroll
        for (int tn = 0; tn < 4; ++tn) {
            short8 b = B[(tk*4 + tn)*64 + lane];
            acc[tn] = __builtin_amdgcn_mfma_f32_16x16x32_bf16(afr[tk], b, acc[tn], 0, 0, 0);
        }
    }
    #pragma unroll
    for (int tn = 0; tn < 4; ++tn) {
        int col = tn*16 + (lane&15);
        if (col < H) {
            float ba = b_A[col];
            #pragma unroll
            for (int reg = 0; reg < 4; ++reg) {
                int row = row0 + (lane>>4)*4 + reg;
                int rg = a0 + row;
                if (rg < NA) Aout[(size_t)rg*H + col] = fmaxf(acc[tn][reg] + ba, 0.f);
            }
        }
    }
}

// ---------------------------------------------------------------------------
extern "C" void kernel_launch(void* const* d_in, const int* in_sizes, int n_in,
                              void* d_out, int out_size, void* d_ws, size_t ws_size,
                              hipStream_t stream)
{
    const float* af   = (const float*)d_in[0];
    const float* pf   = (const float*)d_in[1];
    const int*   seg  = (const int*)d_in[2];
    const int*   a2p  = (const int*)d_in[3];
    const float* W_AA = (const float*)d_in[4];
    const float* b_AA = (const float*)d_in[5];
    const float* W_PA = (const float*)d_in[6];
    const float* b_PA = (const float*)d_in[7];
    const float* W_A  = (const float*)d_in[8];
    const float* b_A  = (const float*)d_in[9];
    const float* W_AP = (const float*)d_in[10];
    const float* b_AP = (const float*)d_in[11];
    const float* W_PP = (const float*)d_in[12];
    const float* b_PP = (const float*)d_in[13];
    const float* W_P  = (const float*)d_in[14];
    const float* b_P  = (const float*)d_in[15];

    float* Aout = (float*)d_out;
    float* Pout = (float*)d_out + (size_t)NA * H;

    float* AA    = (float*)d_ws;               // 10 MB each
    float* U     = AA + (size_t)NA * H;
    float* V     = U  + (size_t)NA * H;
    float* PAsum = V  + (size_t)NA * H;
    ushort* WPf  = (ushort*)(PAsum + (size_t)NA * H);   // 16 KB
    ushort* WAf  = WPf + 4*4*64*8;                      // 16 KB
    ushort* W2f  = WAf + 4*4*64*8;                      // 8 KB

    hipMemsetAsync(PAsum, 0, (size_t)NA * H * sizeof(float), stream);
    k_prep_frags<<<1, 256, 0, stream>>>(W_P, W_A, W_PP, W_PA, WPf, WAf, W2f);
    k_atom_pre<<<(NA + 3) / 4, 256, 0, stream>>>(af, W_AA, b_AA, W_AP, AA, U, V);
    k_pairs<<<NP / 64, 256, 0, stream>>>(pf, seg, a2p, U, V, b_PP, b_PA, b_AP, b_P,
                                         WPf, W2f, PAsum, Pout);
    k_A<<<(NA + 63) / 64, 256, 0, stream>>>(AA, PAsum, WAf, b_A, Aout);
}

// Round 3
// 333.413 us; speedup vs baseline: 2.7182x; 1.2711x over previous
//
#include <hip/hip_runtime.h>
#include <hip/hip_bf16.h>

#define NA 50000
#define NP 1000000
#define FA 75
#define FP 14
#define H  50

typedef __attribute__((ext_vector_type(8))) short short8;
typedef __attribute__((ext_vector_type(4))) float f32x4;

__device__ __forceinline__ ushort f2bf(float f) {
    union { float f; unsigned u; } v; v.f = f;
    unsigned r = v.u + 0x7FFF + ((v.u >> 16) & 1);   // RNE
    return (ushort)(r >> 16);
}
__device__ __forceinline__ float bf2f(ushort u) {
    union { unsigned u; float f; } v; v.u = ((unsigned)u) << 16; return v.f;
}

// ---------------------------------------------------------------------------
// K0: pack weights into MFMA B-fragment order (bf16), zero-padded.
// B-frag 16x16x32: lane l, elem j -> W[k = tk*32+(l>>4)*8+j][col = tn*16+(l&15)]
// WPf/WAf: [tk=4][tn=4][64][8]  (K=128 pad from 100, N=64 pad from 50)
// W2f:     [tn=8][64][8]        (K=32 pad from 14; tn 0..3 = W_PP, 4..7 = W_PA)
// ---------------------------------------------------------------------------
__global__ __launch_bounds__(256) void k_prep_frags(
    const float* __restrict__ W_P, const float* __restrict__ W_A,
    const float* __restrict__ W_PP, const float* __restrict__ W_PA,
    ushort* __restrict__ WPf, ushort* __restrict__ WAf, ushort* __restrict__ W2f)
{
    int t = threadIdx.x;
    for (int idx = t; idx < 4*4*64*8; idx += 256) {
        int j = idx & 7, l = (idx >> 3) & 63, tn = (idx >> 9) & 3, tk = idx >> 11;
        int k = tk*32 + (l>>4)*8 + j;
        int c = tn*16 + (l&15);
        ushort vp = 0, va = 0;
        if (k < 100 && c < 50) { vp = f2bf(W_P[k*50+c]); va = f2bf(W_A[k*50+c]); }
        WPf[idx] = vp; WAf[idx] = va;
    }
    for (int idx = t; idx < 8*64*8; idx += 256) {
        int j = idx & 7, l = (idx >> 3) & 63, tn = idx >> 9;
        int k = (l>>4)*8 + j;
        int c = (tn&3)*16 + (l&15);
        ushort v = 0;
        if (k < 14 && c < 50) v = f2bf(tn < 4 ? W_PP[k*50+c] : W_PA[k*50+c]);
        W2f[idx] = v;
    }
}

// ---------------------------------------------------------------------------
// K1: per-atom precompute.  AA = relu(af@W_AA+b) fp32;
//     UVb[atom][128] bf16: [0..49]=af@W_AP[0:75], [64..113]=af@W_AP[75:150]
// ---------------------------------------------------------------------------
__global__ __launch_bounds__(256) void k_atom_pre(
    const float* __restrict__ af,
    const float* __restrict__ W_AA, const float* __restrict__ b_AA,
    const float* __restrict__ W_AP,
    float* __restrict__ AA, ushort* __restrict__ UVb)
{
    int wave = (blockIdx.x * 256 + threadIdx.x) >> 6;
    int lane = threadIdx.x & 63;
    if (wave >= NA) return;
    const float* afr = af + (size_t)wave * FA;
    if (lane < H) {
        float accA = b_AA[lane], accU = 0.f, accV = 0.f;
        #pragma unroll 5
        for (int k = 0; k < FA; ++k) {
            float a = afr[k];
            accA += a * W_AA[k * H + lane];
            accU += a * W_AP[k * H + lane];
            accV += a * W_AP[(FA + k) * H + lane];
        }
        AA[(size_t)wave * H + lane] = fmaxf(accA, 0.f);
        UVb[(size_t)wave * 128 + lane]      = f2bf(accU);
        UVb[(size_t)wave * 128 + 64 + lane] = f2bf(accV);
    }
}

// ---------------------------------------------------------------------------
// K2: 64 pairs/block (4 waves), single __syncthreads.
//   APs from bf16 UVb gathers; PP/PA via K=32 MFMA (A-frag direct from pf);
//   P = relu(X@W_P+b) via 16 MFMA/wave; PA seg-summed (sorted) via atomics.
// ---------------------------------------------------------------------------
__global__ __launch_bounds__(256) void k_pairs(
    const float* __restrict__ pf, const int* __restrict__ seg, const int* __restrict__ a2p,
    const ushort* __restrict__ UVb,
    const float* __restrict__ b_PP, const float* __restrict__ b_PA,
    const float* __restrict__ b_AP, const float* __restrict__ b_P,
    const ushort* __restrict__ WPf, const ushort* __restrict__ W2f,
    float* __restrict__ PAsum, float* __restrict__ Pout)
{
    __shared__ __align__(16) ushort sX[64][136];    // X bf16: [APs|PP|0pad], K=128
    __shared__ ushort sPA[64][50];                  // PA bf16
    __shared__ int sSeg[64];

    const int t = threadIdx.x;
    const int w = t >> 6, lane = t & 63;
    const int p0 = blockIdx.x * 64;
    const int row0 = w * 16;

    if (t < 64) sSeg[t] = seg[p0 + t];
    for (int idx = t; idx < 64*28; idx += 256) {    // zero X K-pad cols 100..127
        int r = idx / 28, c = 100 + idx % 28;
        sX[r][c] = 0;
    }

    // ---- APs = relu(U_i+V_j+b) + relu(U_j+V_i+b) -> sX[:,0:50] ----
    float bap = (lane < H) ? b_AP[lane] : 0.f;
    #pragma unroll 8
    for (int it = 0; it < 16; ++it) {
        int p = p0 + row0 + it;
        int i = a2p[2*p], j = a2p[2*p+1];
        if (lane < H) {
            float ui = bf2f(UVb[(size_t)i*128 + lane]);
            float vj = bf2f(UVb[(size_t)j*128 + 64 + lane]);
            float uj = bf2f(UVb[(size_t)j*128 + lane]);
            float vi = bf2f(UVb[(size_t)i*128 + 64 + lane]);
            float aps = fmaxf(ui + vj + bap, 0.f) + fmaxf(uj + vi + bap, 0.f);
            sX[row0 + it][lane] = f2bf(aps);
        }
    }

    // ---- PP -> sX[:,50:100], PA -> sPA, one K=32 MFMA pass; A-frag from pf ----
    {
        const int q = lane >> 4;
        const int row = row0 + (lane & 15);
        const float* pfr = pf + (size_t)(p0 + row) * FP;
        short8 a;
        #pragma unroll
        for (int j = 0; j < 8; ++j) {
            int k = q*8 + j;
            float v = (k < FP) ? pfr[k] : 0.f;
            a[j] = (short)f2bf(v);
        }
        const short8* B = (const short8*)W2f;
        #pragma unroll
        for (int tn = 0; tn < 8; ++tn) {
            f32x4 c = {0.f, 0.f, 0.f, 0.f};
            short8 b = B[tn*64 + lane];
            c = __builtin_amdgcn_mfma_f32_16x16x32_bf16(a, b, c, 0, 0, 0);
            int col = (tn&3)*16 + (lane&15);
            if (col < H) {
                float bias = (tn < 4) ? b_PP[col] : b_PA[col];
                #pragma unroll
                for (int reg = 0; reg < 4; ++reg) {
                    int row2 = row0 + (lane>>4)*4 + reg;
                    float v = fmaxf(c[reg] + bias, 0.f);
                    if (tn < 4) sX[row2][H + col] = f2bf(v);
                    else        sPA[row2][col] = f2bf(v);
                }
            }
        }
    }
    __syncthreads();

    // ---- P = relu(X @ W_P + b_P), M=64 N=64 K=128 ----
    {
        short8 afr[4];
        #pragma unroll
        for (int tk = 0; tk < 4; ++tk)
            afr[tk] = *(const short8*)&sX[row0 + (lane&15)][tk*32 + (lane>>4)*8];
        const short8* B = (const short8*)WPf;
        f32x4 acc[4];
        #pragma unroll
        for (int tn = 0; tn < 4; ++tn) acc[tn] = (f32x4){0.f, 0.f, 0.f, 0.f};
        #pragma unroll
        for (int tk = 0; tk < 4; ++tk) {
            #pragma unroll
            for (int tn = 0; tn < 4; ++tn) {
                short8 b = B[(tk*4 + tn)*64 + lane];
                acc[tn] = __builtin_amdgcn_mfma_f32_16x16x32_bf16(afr[tk], b, acc[tn], 0, 0, 0);
            }
        }
        #pragma unroll
        for (int tn = 0; tn < 4; ++tn) {
            int col = tn*16 + (lane&15);
            if (col < H) {
                float bp = b_P[col];
                #pragma unroll
                for (int reg = 0; reg < 4; ++reg) {
                    int row = row0 + (lane>>4)*4 + reg;
                    Pout[(size_t)(p0 + row)*H + col] = fmaxf(acc[tn][reg] + bp, 0.f);
                }
            }
        }
    }

    // ---- segment-sum PA (seg sorted): run-length within 16-row strips ----
    if (t < 200) {
        int c = t % 50, q = t / 50;
        int r0 = q * 16;
        int cur = sSeg[r0];
        float acc = 0.f;
        for (int r = r0; r < r0 + 16; ++r) {
            int s = sSeg[r];
            if (s != cur) { atomicAdd(&PAsum[(size_t)cur*H + c], acc); acc = 0.f; cur = s; }
            acc += bf2f(sPA[r][c]);
        }
        atomicAdd(&PAsum[(size_t)cur*H + c], acc);
    }
}

// ---------------------------------------------------------------------------
// K3: A = relu([AA | PAsum] @ W_A + b_A), 64 atoms/block.
// ---------------------------------------------------------------------------
__global__ __launch_bounds__(256) void k_A(
    const float* __restrict__ AA, const float* __restrict__ PAsum,
    const ushort* __restrict__ WAf, const float* __restrict__ b_A,
    float* __restrict__ Aout)
{
    __shared__ __align__(16) ushort sX[64][136];
    const int t = threadIdx.x, lane = t & 63, w = t >> 6;
    const int a0 = blockIdx.x * 64;
    const int row0 = w * 16;

    for (int idx = t; idx < 64*50; idx += 256) {
        int r = idx / 50, c = idx % 50;
        int rg = a0 + r;
        float aa = 0.f, ps = 0.f;
        if (rg < NA) { aa = AA[(size_t)rg*H + c]; ps = PAsum[(size_t)rg*H + c]; }
        sX[r][c] = f2bf(aa);
        sX[r][H + c] = f2bf(ps);
    }
    for (int idx = t; idx < 64*28; idx += 256) {
        int r = idx / 28, c = 100 + idx % 28;
        sX[r][c] = 0;
    }
    __syncthreads();

    short8 afr[4];
    #pragma unroll
    for (int tk = 0; tk < 4; ++tk)
        afr[tk] = *(const short8*)&sX[row0 + (lane&15)][tk*32 + (lane>>4)*8];
    const short8* B = (const short8*)WAf;
    f32x4 acc[4];
    #pragma unroll
    for (int tn = 0; tn < 4; ++tn) acc[tn] = (f32x4){0.f, 0.f, 0.f, 0.f};
    #pragma unroll
    for (int tk = 0; tk < 4; ++tk) {
        #pragma unroll
        for (int tn = 0; tn < 4; ++tn) {
            short8 b = B[(tk*4 + tn)*64 + lane];
            acc[tn] = __builtin_amdgcn_mfma_f32_16x16x32_bf16(afr[tk], b, acc[tn], 0, 0, 0);
        }
    }
    #pragma unroll
    for (int tn = 0; tn < 4; ++tn) {
        int col = tn*16 + (lane&15);
        if (col < H) {
            float ba = b_A[col];
            #pragma unroll
            for (int reg = 0; reg < 4; ++reg) {
                int row = row0 + (lane>>4)*4 + reg;
                int rg = a0 + row;
                if (rg < NA) Aout[(size_t)rg*H + col] = fmaxf(acc[tn][reg] + ba, 0.f);
            }
        }
    }
}

// ---------------------------------------------------------------------------
extern "C" void kernel_launch(void* const* d_in, const int* in_sizes, int n_in,
                              void* d_out, int out_size, void* d_ws, size_t ws_size,
                              hipStream_t stream)
{
    const float* af   = (const float*)d_in[0];
    const float* pf   = (const float*)d_in[1];
    const int*   seg  = (const int*)d_in[2];
    const int*   a2p  = (const int*)d_in[3];
    const float* W_AA = (const float*)d_in[4];
    const float* b_AA = (const float*)d_in[5];
    const float* W_PA = (const float*)d_in[6];
    const float* b_PA = (const float*)d_in[7];
    const float* W_A  = (const float*)d_in[8];
    const float* b_A  = (const float*)d_in[9];
    const float* W_AP = (const float*)d_in[10];
    const float* b_AP = (const float*)d_in[11];
    const float* W_PP = (const float*)d_in[12];
    const float* b_PP = (const float*)d_in[13];
    const float* W_P  = (const float*)d_in[14];
    const float* b_P  = (const float*)d_in[15];

    float* Aout = (float*)d_out;
    float* Pout = (float*)d_out + (size_t)NA * H;

    float*  AA    = (float*)d_ws;                       // 10 MB
    float*  PAsum = AA + (size_t)NA * H;                // 10 MB
    ushort* UVb   = (ushort*)(PAsum + (size_t)NA * H);  // 12.8 MB
    ushort* WPf   = UVb + (size_t)NA * 128;             // 16 KB
    ushort* WAf   = WPf + 4*4*64*8;                     // 16 KB
    ushort* W2f   = WAf + 4*4*64*8;                     // 8 KB

    hipMemsetAsync(PAsum, 0, (size_t)NA * H * sizeof(float), stream);
    k_prep_frags<<<1, 256, 0, stream>>>(W_P, W_A, W_PP, W_PA, WPf, WAf, W2f);
    k_atom_pre<<<(NA + 3) / 4, 256, 0, stream>>>(af, W_AA, b_AA, W_AP, AA, UVb);
    k_pairs<<<NP / 64, 256, 0, stream>>>(pf, seg, a2p, UVb, b_PP, b_PA, b_AP, b_P,
                                         WPf, W2f, PAsum, Pout);
    k_A<<<(NA + 63) / 64, 256, 0, stream>>>(AA, PAsum, WAf, b_A, Aout);
}

// Round 4
// 267.387 us; speedup vs baseline: 3.3894x; 1.2469x over previous
//
#include <hip/hip_runtime.h>
#include <hip/hip_bf16.h>

#define NA 50000
#define NP 1000000
#define FA 75
#define FP 14
#define H  50

typedef __attribute__((ext_vector_type(8))) short short8;
typedef __attribute__((ext_vector_type(4))) float f32x4;

__device__ __forceinline__ ushort f2bf(float f) {
    union { float f; unsigned u; } v; v.f = f;
    unsigned r = v.u + 0x7FFF + ((v.u >> 16) & 1);   // RNE
    return (ushort)(r >> 16);
}
__device__ __forceinline__ float bf2f(ushort u) {
    union { unsigned u; float f; } v; v.u = ((unsigned)u) << 16; return v.f;
}
__device__ __forceinline__ float bf2f_lo(unsigned u) {
    union { unsigned u; float f; } v; v.u = u << 16; return v.f;
}
__device__ __forceinline__ float bf2f_hi(unsigned u) {
    union { unsigned u; float f; } v; v.u = u & 0xffff0000u; return v.f;
}

// ---------------------------------------------------------------------------
// K0: pack weights into MFMA B-fragment order (bf16), zero-padded.
// B-frag 16x16x32: lane l, elem j -> W[k = tk*32+(l>>4)*8+j][col = tn*16+(l&15)]
// WPf/WAf:  [tk=4][tn=4][64][8]   (K=128 pad from 100, N=64 pad from 50)
// W2f:      [tn=8][64][8]         (K=32 pad from 14; tn 0..3 = W_PP, 4..7 = W_PA)
// WPREf:    [tk=3][tn=12][64][8]  (K=96 pad from 75; N=192: [AA|pad][U|pad][V|pad])
// ---------------------------------------------------------------------------
__global__ __launch_bounds__(256) void k_prep_frags(
    const float* __restrict__ W_P, const float* __restrict__ W_A,
    const float* __restrict__ W_PP, const float* __restrict__ W_PA,
    const float* __restrict__ W_AA, const float* __restrict__ W_AP,
    ushort* __restrict__ WPf, ushort* __restrict__ WAf, ushort* __restrict__ W2f,
    ushort* __restrict__ WPREf)
{
    int t = threadIdx.x;
    for (int idx = t; idx < 4*4*64*8; idx += 256) {
        int j = idx & 7, l = (idx >> 3) & 63, tn = (idx >> 9) & 3, tk = idx >> 11;
        int k = tk*32 + (l>>4)*8 + j;
        int c = tn*16 + (l&15);
        ushort vp = 0, va = 0;
        if (k < 100 && c < 50) { vp = f2bf(W_P[k*50+c]); va = f2bf(W_A[k*50+c]); }
        WPf[idx] = vp; WAf[idx] = va;
    }
    for (int idx = t; idx < 8*64*8; idx += 256) {
        int j = idx & 7, l = (idx >> 3) & 63, tn = idx >> 9;
        int k = (l>>4)*8 + j;
        int c = (tn&3)*16 + (l&15);
        ushort v = 0;
        if (k < 14 && c < 50) v = f2bf(tn < 4 ? W_PP[k*50+c] : W_PA[k*50+c]);
        W2f[idx] = v;
    }
    for (int idx = t; idx < 3*12*64*8; idx += 256) {
        int j = idx & 7, l = (idx >> 3) & 63;
        int g = idx >> 9;            // tk*12+tn
        int tn = g % 12, tk = g / 12;
        int k = tk*32 + (l>>4)*8 + j;
        int sn = tn*16 + (l&15);
        int which = sn >> 6, col = sn & 63;
        ushort v = 0;
        if (k < FA && col < H) {
            float w = (which == 0) ? W_AA[k*H+col]
                    : (which == 1) ? W_AP[k*H+col]
                                   : W_AP[(FA+k)*H+col];
            v = f2bf(w);
        }
        WPREf[idx] = v;
    }
}

// ---------------------------------------------------------------------------
// K1: per-atom precompute via MFMA, 64 atoms/block.
//   [AAb | U | V] = af @ [W_AA | W_AP_u | W_AP_v]  (M=64, K=96, N=192)
//   AAb bf16 [NA][50];  UVi[atom][64] uint, lo16=U, hi16=V (bf16 each).
// ---------------------------------------------------------------------------
__global__ __launch_bounds__(256) void k_atom_pre(
    const float* __restrict__ af, const ushort* __restrict__ WPREf,
    const float* __restrict__ b_AA,
    ushort* __restrict__ AAb, unsigned* __restrict__ UVi)
{
    __shared__ __align__(16) ushort sAF[64][104];   // bf16 af rows, K-pad to 96
    const int t = threadIdx.x, lane = t & 63, w = t >> 6;
    const int a0 = blockIdx.x * 64, row0 = w * 16;

    for (int idx = t; idx < 64*96; idx += 256) {
        int r = idx / 96, c = idx % 96;
        int ag = a0 + r;
        float v = (c < FA && ag < NA) ? af[(size_t)ag*FA + c] : 0.f;
        sAF[r][c] = f2bf(v);
    }
    __syncthreads();

    short8 afr[3];
    #pragma unroll
    for (int tk = 0; tk < 3; ++tk)
        afr[tk] = *(const short8*)&sAF[row0 + (lane&15)][tk*32 + (lane>>4)*8];

    const short8* B = (const short8*)WPREf;
    f32x4 acc[12];
    #pragma unroll
    for (int tn = 0; tn < 12; ++tn) acc[tn] = (f32x4){0.f, 0.f, 0.f, 0.f};
    #pragma unroll
    for (int tk = 0; tk < 3; ++tk) {
        #pragma unroll
        for (int tn = 0; tn < 12; ++tn) {
            short8 b = B[(tk*12 + tn)*64 + lane];
            acc[tn] = __builtin_amdgcn_mfma_f32_16x16x32_bf16(afr[tk], b, acc[tn], 0, 0, 0);
        }
    }

    #pragma unroll
    for (int tn = 0; tn < 4; ++tn) {
        int col = tn*16 + (lane&15);
        if (col < H) {
            float ba = b_AA[col];
            #pragma unroll
            for (int reg = 0; reg < 4; ++reg) {
                int atom = a0 + row0 + (lane>>4)*4 + reg;
                if (atom < NA) {
                    AAb[(size_t)atom*H + col] = f2bf(fmaxf(acc[tn][reg] + ba, 0.f));
                    unsigned pu = f2bf(acc[4 + tn][reg]);
                    unsigned pv = f2bf(acc[8 + tn][reg]);
                    UVi[(size_t)atom*64 + col] = (pv << 16) | pu;
                }
            }
        }
    }
}

// ---------------------------------------------------------------------------
// K2: 64 pairs/block (4 waves), single __syncthreads.
//   APs from packed UVi gathers (2 dwords/pair); PP/PA via K=32 MFMA;
//   P = relu(X@W_P+b) via 16 MFMA/wave; PA seg-summed (sorted) via atomics.
// ---------------------------------------------------------------------------
__global__ __launch_bounds__(256) void k_pairs(
    const float* __restrict__ pf, const int* __restrict__ seg, const int* __restrict__ a2p,
    const unsigned* __restrict__ UVi,
    const float* __restrict__ b_PP, const float* __restrict__ b_PA,
    const float* __restrict__ b_AP, const float* __restrict__ b_P,
    const ushort* __restrict__ WPf, const ushort* __restrict__ W2f,
    float* __restrict__ PAsum, float* __restrict__ Pout)
{
    __shared__ __align__(16) ushort sX[64][136];    // X bf16: [APs|PP|0pad], K=128
    __shared__ ushort sPA[64][50];                  // PA bf16
    __shared__ int sSeg[64];

    const int t = threadIdx.x;
    const int w = t >> 6, lane = t & 63;
    const int p0 = blockIdx.x * 64;
    const int row0 = w * 16;

    if (t < 64) sSeg[t] = seg[p0 + t];
    for (int idx = t; idx < 64*28; idx += 256) {    // zero X K-pad cols 100..127
        int r = idx / 28, c = 100 + idx % 28;
        sX[r][c] = 0;
    }

    // ---- APs = relu(U_i+V_j+b) + relu(U_j+V_i+b) -> sX[:,0:50] ----
    float bap = (lane < H) ? b_AP[lane] : 0.f;
    #pragma unroll 8
    for (int it = 0; it < 16; ++it) {
        int p = p0 + row0 + it;
        int2 ij = ((const int2*)a2p)[p];
        if (lane < H) {
            unsigned uvi = UVi[(size_t)ij.x*64 + lane];
            unsigned uvj = UVi[(size_t)ij.y*64 + lane];
            float ui = bf2f_lo(uvi), vi = bf2f_hi(uvi);
            float uj = bf2f_lo(uvj), vj = bf2f_hi(uvj);
            float aps = fmaxf(ui + vj + bap, 0.f) + fmaxf(uj + vi + bap, 0.f);
            sX[row0 + it][lane] = f2bf(aps);
        }
    }

    // ---- PP -> sX[:,50:100], PA -> sPA, one K=32 MFMA pass; A-frag from pf ----
    {
        const int q = lane >> 4;
        const int row = row0 + (lane & 15);
        const float* pfr = pf + (size_t)(p0 + row) * FP;
        short8 a;
        #pragma unroll
        for (int j = 0; j < 8; ++j) {
            int k = q*8 + j;
            float v = (k < FP) ? pfr[k] : 0.f;
            a[j] = (short)f2bf(v);
        }
        const short8* B = (const short8*)W2f;
        #pragma unroll
        for (int tn = 0; tn < 8; ++tn) {
            f32x4 c = {0.f, 0.f, 0.f, 0.f};
            short8 b = B[tn*64 + lane];
            c = __builtin_amdgcn_mfma_f32_16x16x32_bf16(a, b, c, 0, 0, 0);
            int col = (tn&3)*16 + (lane&15);
            if (col < H) {
                float bias = (tn < 4) ? b_PP[col] : b_PA[col];
                #pragma unroll
                for (int reg = 0; reg < 4; ++reg) {
                    int row2 = row0 + (lane>>4)*4 + reg;
                    float v = fmaxf(c[reg] + bias, 0.f);
                    if (tn < 4) sX[row2][H + col] = f2bf(v);
                    else        sPA[row2][col] = f2bf(v);
                }
            }
        }
    }
    __syncthreads();

    // ---- P = relu(X @ W_P + b_P), M=64 N=64 K=128 ----
    {
        short8 afr[4];
        #pragma unroll
        for (int tk = 0; tk < 4; ++tk)
            afr[tk] = *(const short8*)&sX[row0 + (lane&15)][tk*32 + (lane>>4)*8];
        const short8* B = (const short8*)WPf;
        f32x4 acc[4];
        #pragma unroll
        for (int tn = 0; tn < 4; ++tn) acc[tn] = (f32x4){0.f, 0.f, 0.f, 0.f};
        #pragma unroll
        for (int tk = 0; tk < 4; ++tk) {
            #pragma unroll
            for (int tn = 0; tn < 4; ++tn) {
                short8 b = B[(tk*4 + tn)*64 + lane];
                acc[tn] = __builtin_amdgcn_mfma_f32_16x16x32_bf16(afr[tk], b, acc[tn], 0, 0, 0);
            }
        }
        #pragma unroll
        for (int tn = 0; tn < 4; ++tn) {
            int col = tn*16 + (lane&15);
            if (col < H) {
                float bp = b_P[col];
                #pragma unroll
                for (int reg = 0; reg < 4; ++reg) {
                    int row = row0 + (lane>>4)*4 + reg;
                    Pout[(size_t)(p0 + row)*H + col] = fmaxf(acc[tn][reg] + bp, 0.f);
                }
            }
        }
    }

    // ---- segment-sum PA (seg sorted): run-length within 16-row strips ----
    if (t < 200) {
        int c = t % 50, q = t / 50;
        int r0 = q * 16;
        int cur = sSeg[r0];
        float acc = 0.f;
        for (int r = r0; r < r0 + 16; ++r) {
            int s = sSeg[r];
            if (s != cur) { atomicAdd(&PAsum[(size_t)cur*H + c], acc); acc = 0.f; cur = s; }
            acc += bf2f(sPA[r][c]);
        }
        atomicAdd(&PAsum[(size_t)cur*H + c], acc);
    }
}

// ---------------------------------------------------------------------------
// K3: A = relu([AAb | PAsum] @ W_A + b_A), 64 atoms/block.
// ---------------------------------------------------------------------------
__global__ __launch_bounds__(256) void k_A(
    const ushort* __restrict__ AAb, const float* __restrict__ PAsum,
    const ushort* __restrict__ WAf, const float* __restrict__ b_A,
    float* __restrict__ Aout)
{
    __shared__ __align__(16) ushort sX[64][136];
    const int t = threadIdx.x, lane = t & 63, w = t >> 6;
    const int a0 = blockIdx.x * 64;
    const int row0 = w * 16;

    for (int idx = t; idx < 64*50; idx += 256) {
        int r = idx / 50, c = idx % 50;
        int rg = a0 + r;
        ushort aa = 0; float ps = 0.f;
        if (rg < NA) { aa = AAb[(size_t)rg*H + c]; ps = PAsum[(size_t)rg*H + c]; }
        sX[r][c] = aa;
        sX[r][H + c] = f2bf(ps);
    }
    for (int idx = t; idx < 64*28; idx += 256) {
        int r = idx / 28, c = 100 + idx % 28;
        sX[r][c] = 0;
    }
    __syncthreads();

    short8 afr[4];
    #pragma unroll
    for (int tk = 0; tk < 4; ++tk)
        afr[tk] = *(const short8*)&sX[row0 + (lane&15)][tk*32 + (lane>>4)*8];
    const short8* B = (const short8*)WAf;
    f32x4 acc[4];
    #pragma unroll
    for (int tn = 0; tn < 4; ++tn) acc[tn] = (f32x4){0.f, 0.f, 0.f, 0.f};
    #pragma unroll
    for (int tk = 0; tk < 4; ++tk) {
        #pragma unroll
        for (int tn = 0; tn < 4; ++tn) {
            short8 b = B[(tk*4 + tn)*64 + lane];
            acc[tn] = __builtin_amdgcn_mfma_f32_16x16x32_bf16(afr[tk], b, acc[tn], 0, 0, 0);
        }
    }
    #pragma unroll
    for (int tn = 0; tn < 4; ++tn) {
        int col = tn*16 + (lane&15);
        if (col < H) {
            float ba = b_A[col];
            #pragma unroll
            for (int reg = 0; reg < 4; ++reg) {
                int row = row0 + (lane>>4)*4 + reg;
                int rg = a0 + row;
                if (rg < NA) Aout[(size_t)rg*H + col] = fmaxf(acc[tn][reg] + ba, 0.f);
            }
        }
    }
}

// ---------------------------------------------------------------------------
extern "C" void kernel_launch(void* const* d_in, const int* in_sizes, int n_in,
                              void* d_out, int out_size, void* d_ws, size_t ws_size,
                              hipStream_t stream)
{
    const float* af   = (const float*)d_in[0];
    const float* pf   = (const float*)d_in[1];
    const int*   seg  = (const int*)d_in[2];
    const int*   a2p  = (const int*)d_in[3];
    const float* W_AA = (const float*)d_in[4];
    const float* b_AA = (const float*)d_in[5];
    const float* W_PA = (const float*)d_in[6];
    const float* b_PA = (const float*)d_in[7];
    const float* W_A  = (const float*)d_in[8];
    const float* b_A  = (const float*)d_in[9];
    const float* W_AP = (const float*)d_in[10];
    const float* b_AP = (const float*)d_in[11];
    const float* W_PP = (const float*)d_in[12];
    const float* b_PP = (const float*)d_in[13];
    const float* W_P  = (const float*)d_in[14];
    const float* b_P  = (const float*)d_in[15];

    float* Aout = (float*)d_out;
    float* Pout = (float*)d_out + (size_t)NA * H;

    ushort*   AAb   = (ushort*)d_ws;                         // 5 MB
    float*    PAsum = (float*)(AAb + (size_t)NA * H);        // 10 MB
    unsigned* UVi   = (unsigned*)(PAsum + (size_t)NA * H);   // 12.8 MB
    ushort*   WPf   = (ushort*)(UVi + (size_t)NA * 64);      // 16 KB
    ushort*   WAf   = WPf + 4*4*64*8;                        // 16 KB
    ushort*   W2f   = WAf + 4*4*64*8;                        // 8 KB
    ushort*   WPREf = W2f + 8*64*8;                          // 36 KB

    hipMemsetAsync(PAsum, 0, (size_t)NA * H * sizeof(float), stream);
    k_prep_frags<<<1, 256, 0, stream>>>(W_P, W_A, W_PP, W_PA, W_AA, W_AP,
                                        WPf, WAf, W2f, WPREf);
    k_atom_pre<<<(NA + 63) / 64, 256, 0, stream>>>(af, WPREf, b_AA, AAb, UVi);
    k_pairs<<<NP / 64, 256, 0, stream>>>(pf, seg, a2p, UVi, b_PP, b_PA, b_AP, b_P,
                                         WPf, W2f, PAsum, Pout);
    k_A<<<(NA + 63) / 64, 256, 0, stream>>>(AAb, PAsum, WAf, b_A, Aout);
}